// Round 3
// baseline (41.685 us; speedup 1.0000x reference)
//
#include <hip/hip_runtime.h>
#include <hip/hip_bf16.h>

// R14 = structural bisect of R13's failure. R13 (absmax 0.38) shared with R12:
// {prepass images, gl_lds copy, K-single-buffer+mid-barrier, WS table, (256,5)}.
// R14 keeps ONLY the prepass + DMA-copy pieces and hosts them in the VERBATIM
// R11 sync skeleton (verified passing, 38.2us):
//   - K AND V double-buffered, ONE __syncthreads per tile.
//   - DMA for tile t+1 issued at the exact program point of R11's load_kv(t+1)
//     (right after the top barrier), targeting buffers [bs^1] whose last reads
//     drained at that barrier -- identical dbuf discipline, no new sync.
//   - rank table back in-kernel (R11's PsB overlay, verified), no WS table.
//   - __launch_bounds__(256,4), LDS 40960 (4 blocks/CU), as R11.
// Deltas vs verified R11 are ONLY: (i) prep_kv writes bf16 swizzled LDS tile
// images (same swz16/swz8, same thread mapping as R11's store_kv) to ws;
// (ii) main staging = offset-preserving global_load_lds(16B) x4/thread of
// those images (pre-swizzled source + linear dest + swizzled read = the
// documented-correct pattern). Kills the per-tile 16x-redundant
// load->wait->cvt_pk->pack->ds_write chain (~50 VALU + in-iteration global
// latency per wave-tile).
// ws_size guard: needs 16 MiB; else fall back to verbatim R11.

#define NB    64
#define LQ    1024
#define LK    1024
#define DH    64
#define KVT   64
#define QT    64
#define NITEMS (NB * (LQ / QT))      // 1024
#define NEGF  1.0e30f
#define SC2   0.18033688011112042f   // 0.125 * log2(e)
#define THR   8.0f                   // defer-max threshold (log2 units)
#define IMG_BT    16384              // bytes per (b,t): K image 8K + V image 8K
#define WS_NEEDED ((size_t)NB * 16 * IMG_BT)   // 16 MiB

typedef __attribute__((ext_vector_type(8))) short    bf8;
typedef __attribute__((ext_vector_type(8))) ushort   u16x8;
typedef __attribute__((ext_vector_type(4))) ushort   u16x4;
typedef __attribute__((ext_vector_type(4))) float    f4;

__device__ __forceinline__ ushort2 cvt2(float a, float b) {   // v_cvt_pk_bf16_f32
    float2 f; f.x = a; f.y = b;
    __hip_bfloat162 h = __float22bfloat162_rn(f);
    union { __hip_bfloat162 h2; ushort2 u2; } u;
    u.h2 = h;
    return u.u2;
}
__device__ __forceinline__ int swz16(int row, int colbyte) {  // K, P tiles
    return row * 128 + ((((colbyte >> 4) ^ (row & 7)) << 4) | (colbyte & 15));
}
__device__ __forceinline__ int swz8(int row, int colbyte) {   // V^T tile
    return row * 128 + ((((colbyte >> 3) ^ (row & 15)) << 3) | (colbyte & 7));
}
__device__ __forceinline__ void gl16(const void* g, void* l) { // 16B global->LDS DMA
    __builtin_amdgcn_global_load_lds(
        (const __attribute__((address_space(1))) unsigned int*)g,
        (__attribute__((address_space(3))) unsigned int*)l, 16, 0, 0);
}

// ---------------- prepass: K/V -> bf16 swizzled LDS images in ws ------------
// Byte-for-byte the image R11's store_kv would have produced in LDS.
__global__ __launch_bounds__(256)
void prep_kv(const float* __restrict__ K, const float* __restrict__ V,
             const int* __restrict__ VL, ushort* __restrict__ WS) {
    const int bt = blockIdx.x;            // 0..1023 = b*16 + t
    const int b = bt >> 4, t = bt & 15;
    const int tid = threadIdx.x;

    const int nt = (VL[b] + KVT - 1) >> 6;
    if (t >= nt) return;                  // never read by main kernel

    const int srow = tid >> 3, sslot = tid & 7;   // K rows srow, srow+32
    const int vkp  = tid >> 4, vj = tid & 15;     // V keys 4vkp.., f4-col vj
    const f4* Kb4 = (const f4*)(K + (size_t)b * LK * DH);
    const f4* Vb4 = (const f4*)(V + (size_t)b * LK * DH);
    const int k0 = t * KVT;

    f4 kr0 = Kb4[(k0 + srow) * 16 + sslot * 2];
    f4 kr1 = Kb4[(k0 + srow) * 16 + sslot * 2 + 1];
    f4 kr2 = Kb4[(k0 + srow + 32) * 16 + sslot * 2];
    f4 kr3 = Kb4[(k0 + srow + 32) * 16 + sslot * 2 + 1];
    f4 vr0 = Vb4[(k0 + 4 * vkp + 0) * 16 + vj];
    f4 vr1 = Vb4[(k0 + 4 * vkp + 1) * 16 + vj];
    f4 vr2 = Vb4[(k0 + 4 * vkp + 2) * 16 + vj];
    f4 vr3 = Vb4[(k0 + 4 * vkp + 3) * 16 + vj];

    char* kd = (char*)WS + (size_t)bt * IMG_BT;   // K image (swz16)
    {
        ushort2 c0 = cvt2(kr0[0], kr0[1]), c1 = cvt2(kr0[2], kr0[3]);
        ushort2 c2 = cvt2(kr1[0], kr1[1]), c3 = cvt2(kr1[2], kr1[3]);
        u16x8 w = {c0.x, c0.y, c1.x, c1.y, c2.x, c2.y, c3.x, c3.y};
        *(u16x8*)(kd + swz16(srow, sslot * 16)) = w;
    }
    {
        ushort2 c0 = cvt2(kr2[0], kr2[1]), c1 = cvt2(kr2[2], kr2[3]);
        ushort2 c2 = cvt2(kr3[0], kr3[1]), c3 = cvt2(kr3[2], kr3[3]);
        u16x8 w = {c0.x, c0.y, c1.x, c1.y, c2.x, c2.y, c3.x, c3.y};
        *(u16x8*)(kd + swz16(srow + 32, sslot * 16)) = w;
    }
    char* vd = kd + 8192;                          // V^T image (swz8)
    #pragma unroll
    for (int c = 0; c < 4; ++c) {                  // transpose: d = 4*vj+c
        ushort2 a01 = cvt2(vr0[c], vr1[c]), a23 = cvt2(vr2[c], vr3[c]);
        u16x4 p = {a01.x, a01.y, a23.x, a23.y};
        *(u16x4*)(vd + swz8(4 * vj + c, vkp * 8)) = p;
    }
}

// ---------------- main: R11 skeleton, DMA staging of prepass images ---------
__global__ __launch_bounds__(256, 4)
void attn_v14(const float* __restrict__ Q, const int* __restrict__ VL,
              const ushort* __restrict__ WS, float* __restrict__ O) {
    __shared__ ushort KsB[2][KVT * DH];   // swz16 [key][d]      16 KB dbuf
    __shared__ ushort VtB[2][DH * KVT];   // swz8  [d][key]      16 KB dbuf
    __shared__ ushort PsB[4][16 * KVT];   // swz16 [q][key]/wave  8 KB => 40960

    const int tid = threadIdx.x;
    const int wid = tid >> 6, l = tid & 63, g = l >> 4, a = l & 15;

    // ---- in-kernel stratified-LPT schedule (R11 verbatim; table on PsB) ----
    ushort* sb = &PsB[0][0];              // 64 entries; dead before 1st P write
    if (tid < NB) {
        const int ntb = (VL[tid] + KVT - 1) >> 6;
        int r = 0;
        for (int j = 0; j < NB; ++j) {
            const int ntj = (VL[j] + KVT - 1) >> 6;
            r += (int)((ntj > ntb) | ((ntj == ntb) & (j < tid)));
        }
        sb[r] = (ushort)tid;              // rank -> batch (desc nt, tie asc)
    }
    __syncthreads();
    const int xcd  = blockIdx.x & 7;      // HW: block i -> XCD i%8
    const int slot = blockIdx.x >> 3;     // 0..127 within XCD
    const int rank = xcd + ((slot >> 4) << 3);   // XCD x owns ranks {x,x+8,..}
    const int b    = sb[rank];
    const int qbase = (slot & 15) * QT;
    const int valid = VL[b];              // 1..1024
    const int nt = (valid + KVT - 1) >> 6;

    // staging: offset-preserving DMA of prepass images, 2x1KB per wave each
    const char* img = (const char*)WS + (size_t)b * (16 * IMG_BT);
    auto stageK = [&](int t, int bs) {
        const char* gsrc = img + (size_t)t * IMG_BT + wid * 2048 + l * 16;
        char* d = (char*)&KsB[bs][0] + wid * 2048;
        gl16(gsrc, d); gl16(gsrc + 1024, d + 1024);
    };
    auto stageV = [&](int t, int bs) {
        const char* gsrc = img + (size_t)t * IMG_BT + 8192 + wid * 2048 + l * 16;
        char* d = (char*)&VtB[bs][0] + wid * 2048;
        gl16(gsrc, d); gl16(gsrc + 1024, d + 1024);
    };
    stageK(0, 0); stageV(0, 0);           // in flight under Q-frag build

    // Q fragment (B-operand), pre-scaled by SC2: col=a (q-row), k=32kblk+8g+i
    const float* Qr = Q + ((size_t)b * LQ + qbase + wid * 16 + a) * DH;
    bf8 qa[2];
    #pragma unroll
    for (int kblk = 0; kblk < 2; ++kblk) {
        f4 x = *(const f4*)(Qr + kblk * 32 + g * 8);
        f4 y = *(const f4*)(Qr + kblk * 32 + g * 8 + 4);
        ushort2 c0 = cvt2(x[0] * SC2, x[1] * SC2), c1 = cvt2(x[2] * SC2, x[3] * SC2);
        ushort2 c2 = cvt2(y[0] * SC2, y[1] * SC2), c3 = cvt2(y[2] * SC2, y[3] * SC2);
        qa[kblk][0] = (short)c0.x; qa[kblk][1] = (short)c0.y;
        qa[kblk][2] = (short)c1.x; qa[kblk][3] = (short)c1.y;
        qa[kblk][4] = (short)c2.x; qa[kblk][5] = (short)c2.y;
        qa[kblk][6] = (short)c3.x; qa[kblk][7] = (short)c3.y;
    }
    const bf8 ones = {0x3F80, 0x3F80, 0x3F80, 0x3F80,
                      0x3F80, 0x3F80, 0x3F80, 0x3F80};   // bf16 1.0 x8

    f4 oacc[4];
    #pragma unroll
    for (int n = 0; n < 4; ++n) oacc[n] = f4{0.f, 0.f, 0.f, 0.f};
    f4 lacc = f4{0.f, 0.f, 0.f, 0.f};   // l per q-row 4g+r (epilogue layout)
    float m_run = -NEGF;                // per-lane: q-row = a

    for (int t = 0; t < nt; ++t) {
        const int bs = t & 1;
        __syncthreads();                   // buf[bs] DMA landed (vmcnt drain);
                                           // buf[bs^1] reads of t-1 drained
        if (t + 1 < nt) {                  // R11's load_kv(t+1) program point
            stageK(t + 1, bs ^ 1);
            stageV(t + 1, bs ^ 1);
        }
        __builtin_amdgcn_sched_barrier(0); // keep DMA issue early

        // ---- S^T = K Q^T (pre-scaled): lane(g,a) -> S[q=a][key=16n+4g+r] ----
        const char* kd = (const char*)&KsB[bs][0];
        f4 sacc[4];
        #pragma unroll
        for (int n = 0; n < 4; ++n) sacc[n] = f4{0.f, 0.f, 0.f, 0.f};
        __builtin_amdgcn_s_setprio(1);
        #pragma unroll
        for (int n = 0; n < 4; ++n)
            #pragma unroll
            for (int kblk = 0; kblk < 2; ++kblk) {
                bf8 kb = *(const bf8*)(kd + swz16(n * 16 + a, kblk * 64 + g * 16));
                sacc[n] = __builtin_amdgcn_mfma_f32_16x16x32_bf16(
                    kb, qa[kblk], sacc[n], 0, 0, 0);   // A=K, B=Q
            }
        __builtin_amdgcn_s_setprio(0);

        float s[4][4];
        const int kmax = valid - t * KVT;
        #pragma unroll
        for (int n = 0; n < 4; ++n)
            #pragma unroll
            for (int r = 0; r < 4; ++r) s[n][r] = sacc[n][r];
        if (kmax < KVT) {
            #pragma unroll
            for (int n = 0; n < 4; ++n)
                #pragma unroll
                for (int r = 0; r < 4; ++r)
                    if (16 * n + 4 * g + r >= kmax) s[n][r] = -NEGF;
        }

        // ---- softmax max: in-lane over 16 keys + 2 shfl over g ----
        float tm = s[0][0];
        #pragma unroll
        for (int n = 0; n < 4; ++n)
            #pragma unroll
            for (int r = 0; r < 4; ++r) tm = fmaxf(tm, s[n][r]);
        tm = fmaxf(tm, __shfl_xor(tm, 16));
        tm = fmaxf(tm, __shfl_xor(tm, 32));

        float rs_ = 1.0f;                     // T13 defer-max
        const bool skip = __all(tm <= m_run + THR);
        if (!skip) {
            const float mnew = fmaxf(m_run, tm);
            rs_ = __builtin_exp2f(m_run - mnew);   // tile0: exp2(-inf)=0
            m_run = mnew;
        }

        float p[4][4];
        #pragma unroll
        for (int n = 0; n < 4; ++n)
            #pragma unroll
            for (int r = 0; r < 4; ++r)
                p[n][r] = __builtin_exp2f(s[n][r] - m_run);   // masked -> 0

        if (!skip) {   // rescale O,l rows (q=4g+r)
            float rr[4];
            #pragma unroll
            for (int r = 0; r < 4; ++r) rr[r] = __shfl(rs_, 4 * g + r);
            #pragma unroll
            for (int n = 0; n < 4; ++n)
                #pragma unroll
                for (int r = 0; r < 4; ++r) oacc[n][r] *= rr[r];
            #pragma unroll
            for (int r = 0; r < 4; ++r) lacc[r] *= rr[r];
        }

        // P -> per-wave LDS: b64 chunks, keys 16n+4g..+3 contiguous
        char* pbase = (char*)&PsB[wid][0];
        #pragma unroll
        for (int n = 0; n < 4; ++n) {
            ushort2 a01 = cvt2(p[n][0], p[n][1]), a23 = cvt2(p[n][2], p[n][3]);
            u16x4 w4 = {a01.x, a01.y, a23.x, a23.y};
            *(u16x4*)(pbase + swz16(a, 32 * n + 8 * g)) = w4;
        }

        // ---- O += P V ; l += P * ones ----
        const char* vd = (const char*)&VtB[bs][0];
        __builtin_amdgcn_s_setprio(1);
        #pragma unroll
        for (int kblk = 0; kblk < 2; ++kblk) {
            bf8 pa = *(const bf8*)(pbase + swz16(a, kblk * 64 + g * 16));
            const int cb = kblk * 64 + g * 16;
            #pragma unroll
            for (int n = 0; n < 4; ++n) {
                u16x4 lo = *(const u16x4*)(vd + swz8(n * 16 + a, cb));
                u16x4 hi = *(const u16x4*)(vd + swz8(n * 16 + a, cb + 8));
                bf8 vb_ = {(short)lo[0], (short)lo[1], (short)lo[2], (short)lo[3],
                           (short)hi[0], (short)hi[1], (short)hi[2], (short)hi[3]};
                oacc[n] = __builtin_amdgcn_mfma_f32_16x16x32_bf16(
                    pa, vb_, oacc[n], 0, 0, 0);
            }
            lacc = __builtin_amdgcn_mfma_f32_16x16x32_bf16(pa, ones, lacc, 0, 0, 0);
        }
        __builtin_amdgcn_s_setprio(0);
    }

    // ---- epilogue: O[q=4g+r][d=16n+a] / l (lacc already row-layout) ----
    float iv[4];
    #pragma unroll
    for (int r = 0; r < 4; ++r) iv[r] = 1.0f / lacc[r];
    float* Ob = O + ((size_t)b * LQ + qbase + wid * 16) * DH;
    #pragma unroll
    for (int n = 0; n < 4; ++n)
        #pragma unroll
        for (int r = 0; r < 4; ++r)
            Ob[(size_t)(4 * g + r) * DH + 16 * n + a] = oacc[n][r] * iv[r];
}

// ---------------- fallback: verbatim R11 kernel (verified 38.2 us) ----------
__global__ __launch_bounds__(256, 4)
void attn_v11(const float* __restrict__ Q, const float* __restrict__ K,
              const float* __restrict__ V, const int* __restrict__ VL,
              float* __restrict__ O) {
    __shared__ ushort KsB[2][KVT * DH];   // swz16 [key][d]      16 KB
    __shared__ ushort VtB[2][DH * KVT];   // swz8  [d][key]      16 KB
    __shared__ ushort PsB[4][16 * KVT];   // swz16 [q][key]/wave  8 KB => 40960

    const int tid = threadIdx.x;
    const int wid = tid >> 6, l = tid & 63, g = l >> 4, a = l & 15;

    ushort* sb = &PsB[0][0];              // 64 entries; dead before 1st P write
    if (tid < NB) {
        const int ntb = (VL[tid] + KVT - 1) >> 6;
        int r = 0;
        for (int j = 0; j < NB; ++j) {
            const int ntj = (VL[j] + KVT - 1) >> 6;
            r += (int)((ntj > ntb) | ((ntj == ntb) & (j < tid)));
        }
        sb[r] = (ushort)tid;              // rank -> batch (desc nt, tie asc)
    }
    __syncthreads();
    const int xcd  = blockIdx.x & 7;
    const int slot = blockIdx.x >> 3;
    const int rank = xcd + ((slot >> 4) << 3);
    const int b    = sb[rank];
    const int qbase = (slot & 15) * QT;
    const int valid = VL[b];
    const int nt = (valid + KVT - 1) >> 6;

    const float* Qr = Q + ((size_t)b * LQ + qbase + wid * 16 + a) * DH;
    bf8 qa[2];
    #pragma unroll
    for (int kblk = 0; kblk < 2; ++kblk) {
        f4 x = *(const f4*)(Qr + kblk * 32 + g * 8);
        f4 y = *(const f4*)(Qr + kblk * 32 + g * 8 + 4);
        ushort2 c0 = cvt2(x[0] * SC2, x[1] * SC2), c1 = cvt2(x[2] * SC2, x[3] * SC2);
        ushort2 c2 = cvt2(y[0] * SC2, y[1] * SC2), c3 = cvt2(y[2] * SC2, y[3] * SC2);
        qa[kblk][0] = (short)c0.x; qa[kblk][1] = (short)c0.y;
        qa[kblk][2] = (short)c1.x; qa[kblk][3] = (short)c1.y;
        qa[kblk][4] = (short)c2.x; qa[kblk][5] = (short)c2.y;
        qa[kblk][6] = (short)c3.x; qa[kblk][7] = (short)c3.y;
    }
    const bf8 ones = {0x3F80, 0x3F80, 0x3F80, 0x3F80,
                      0x3F80, 0x3F80, 0x3F80, 0x3F80};

    const int srow = tid >> 3, sslot = tid & 7;
    const int vkp  = tid >> 4, vj = tid & 15;
    const f4* Kb4 = (const f4*)(K + (size_t)b * LK * DH);
    const f4* Vb4 = (const f4*)(V + (size_t)b * LK * DH);

    f4 kr0, kr1, kr2, kr3, vr0, vr1, vr2, vr3;
    auto load_kv = [&](int k0) {
        kr0 = Kb4[(k0 + srow) * 16 + sslot * 2];
        kr1 = Kb4[(k0 + srow) * 16 + sslot * 2 + 1];
        kr2 = Kb4[(k0 + srow + 32) * 16 + sslot * 2];
        kr3 = Kb4[(k0 + srow + 32) * 16 + sslot * 2 + 1];
        vr0 = Vb4[(k0 + 4 * vkp + 0) * 16 + vj];
        vr1 = Vb4[(k0 + 4 * vkp + 1) * 16 + vj];
        vr2 = Vb4[(k0 + 4 * vkp + 2) * 16 + vj];
        vr3 = Vb4[(k0 + 4 * vkp + 3) * 16 + vj];
    };
    auto store_kv = [&](int bs) {
        char* kd = (char*)&KsB[bs][0];
        {
            ushort2 c0 = cvt2(kr0[0], kr0[1]), c1 = cvt2(kr0[2], kr0[3]);
            ushort2 c2 = cvt2(kr1[0], kr1[1]), c3 = cvt2(kr1[2], kr1[3]);
            u16x8 w = {c0.x, c0.y, c1.x, c1.y, c2.x, c2.y, c3.x, c3.y};
            *(u16x8*)(kd + swz16(srow, sslot * 16)) = w;
        }
        {
            ushort2 c0 = cvt2(kr2[0], kr2[1]), c1 = cvt2(kr2[2], kr2[3]);
            ushort2 c2 = cvt2(kr3[0], kr3[1]), c3 = cvt2(kr3[2], kr3[3]);
            u16x8 w = {c0.x, c0.y, c1.x, c1.y, c2.x, c2.y, c3.x, c3.y};
            *(u16x8*)(kd + swz16(srow + 32, sslot * 16)) = w;
        }
        char* vd = (char*)&VtB[bs][0];
        #pragma unroll
        for (int c = 0; c < 4; ++c) {
            ushort2 a01 = cvt2(vr0[c], vr1[c]), a23 = cvt2(vr2[c], vr3[c]);
            u16x4 p = {a01.x, a01.y, a23.x, a23.y};
            *(u16x4*)(vd + swz8(4 * vj + c, vkp * 8)) = p;
        }
    };

    f4 oacc[4];
    #pragma unroll
    for (int n = 0; n < 4; ++n) oacc[n] = f4{0.f, 0.f, 0.f, 0.f};
    f4 lacc = f4{0.f, 0.f, 0.f, 0.f};
    float m_run = -NEGF;

    load_kv(0);
    store_kv(0);
    for (int t = 0; t < nt; ++t) {
        const int bs = t & 1;
        __syncthreads();
        if (t + 1 < nt) load_kv((t + 1) * KVT);
        __builtin_amdgcn_sched_barrier(0);

        const char* kd = (const char*)&KsB[bs][0];
        f4 sacc[4];
        #pragma unroll
        for (int n = 0; n < 4; ++n) sacc[n] = f4{0.f, 0.f, 0.f, 0.f};
        __builtin_amdgcn_s_setprio(1);
        #pragma unroll
        for (int n = 0; n < 4; ++n)
            #pragma unroll
            for (int kblk = 0; kblk < 2; ++kblk) {
                bf8 kb = *(const bf8*)(kd + swz16(n * 16 + a, kblk * 64 + g * 16));
                sacc[n] = __builtin_amdgcn_mfma_f32_16x16x32_bf16(
                    kb, qa[kblk], sacc[n], 0, 0, 0);
            }
        __builtin_amdgcn_s_setprio(0);

        float s[4][4];
        const int kmax = valid - t * KVT;
        #pragma unroll
        for (int n = 0; n < 4; ++n)
            #pragma unroll
            for (int r = 0; r < 4; ++r) s[n][r] = sacc[n][r];
        if (kmax < KVT) {
            #pragma unroll
            for (int n = 0; n < 4; ++n)
                #pragma unroll
                for (int r = 0; r < 4; ++r)
                    if (16 * n + 4 * g + r >= kmax) s[n][r] = -NEGF;
        }

        float tm = s[0][0];
        #pragma unroll
        for (int n = 0; n < 4; ++n)
            #pragma unroll
            for (int r = 0; r < 4; ++r) tm = fmaxf(tm, s[n][r]);
        tm = fmaxf(tm, __shfl_xor(tm, 16));
        tm = fmaxf(tm, __shfl_xor(tm, 32));

        float rs_ = 1.0f;
        const bool skip = __all(tm <= m_run + THR);
        if (!skip) {
            const float mnew = fmaxf(m_run, tm);
            rs_ = __builtin_exp2f(m_run - mnew);
            m_run = mnew;
        }

        float p[4][4];
        #pragma unroll
        for (int n = 0; n < 4; ++n)
            #pragma unroll
            for (int r = 0; r < 4; ++r)
                p[n][r] = __builtin_exp2f(s[n][r] - m_run);

        if (!skip) {
            float rr[4];
            #pragma unroll
            for (int r = 0; r < 4; ++r) rr[r] = __shfl(rs_, 4 * g + r);
            #pragma unroll
            for (int n = 0; n < 4; ++n)
                #pragma unroll
                for (int r = 0; r < 4; ++r) oacc[n][r] *= rr[r];
            #pragma unroll
            for (int r = 0; r < 4; ++r) lacc[r] *= rr[r];
        }

        char* pbase = (char*)&PsB[wid][0];
        #pragma unroll
        for (int n = 0; n < 4; ++n) {
            ushort2 a01 = cvt2(p[n][0], p[n][1]), a23 = cvt2(p[n][2], p[n][3]);
            u16x4 w4 = {a01.x, a01.y, a23.x, a23.y};
            *(u16x4*)(pbase + swz16(a, 32 * n + 8 * g)) = w4;
        }

        const char* vd = (const char*)&VtB[bs][0];
        __builtin_amdgcn_s_setprio(1);
        #pragma unroll
        for (int kblk = 0; kblk < 2; ++kblk) {
            bf8 pa = *(const bf8*)(pbase + swz16(a, kblk * 64 + g * 16));
            const int cb = kblk * 64 + g * 16;
            #pragma unroll
            for (int n = 0; n < 4; ++n) {
                u16x4 lo = *(const u16x4*)(vd + swz8(n * 16 + a, cb));
                u16x4 hi = *(const u16x4*)(vd + swz8(n * 16 + a, cb + 8));
                bf8 vb = {(short)lo[0], (short)lo[1], (short)lo[2], (short)lo[3],
                          (short)hi[0], (short)hi[1], (short)hi[2], (short)hi[3]};
                oacc[n] = __builtin_amdgcn_mfma_f32_16x16x32_bf16(
                    pa, vb, oacc[n], 0, 0, 0);
            }
            lacc = __builtin_amdgcn_mfma_f32_16x16x32_bf16(pa, ones, lacc, 0, 0, 0);
        }
        __builtin_amdgcn_s_setprio(0);

        if (t + 1 < nt) store_kv(bs ^ 1);
    }

    float iv[4];
    #pragma unroll
    for (int r = 0; r < 4; ++r) iv[r] = 1.0f / lacc[r];
    float* Ob = O + ((size_t)b * LQ + qbase + wid * 16) * DH;
    #pragma unroll
    for (int n = 0; n < 4; ++n)
        #pragma unroll
        for (int r = 0; r < 4; ++r)
            Ob[(size_t)(4 * g + r) * DH + 16 * n + a] = oacc[n][r] * iv[r];
}

extern "C" void kernel_launch(void* const* d_in, const int* in_sizes, int n_in,
                              void* d_out, int out_size, void* d_ws, size_t ws_size,
                              hipStream_t stream) {
    const float* Q  = (const float*)d_in[0];
    const float* K  = (const float*)d_in[1];
    const float* V  = (const float*)d_in[2];
    const int*   VL = (const int*)d_in[3];
    float* O = (float*)d_out;

    if (d_ws != nullptr && ws_size >= WS_NEEDED) {
        // ws layout: [0, 16 MiB): 1024 x 16 KB (b,t) swizzled bf16 images
        ushort* WS = (ushort*)d_ws;
        prep_kv<<<NB * 16, 256, 0, stream>>>(K, V, VL, WS);
        attn_v14<<<NITEMS, 256, 0, stream>>>(Q, VL, WS, O);
    } else {
        attn_v11<<<NITEMS, 256, 0, stream>>>(Q, K, V, VL, O);
    }
}

// Round 4
// 35.499 us; speedup vs baseline: 1.1743x; 1.1743x over previous
//
#include <hip/hip_runtime.h>
#include <hip/hip_bf16.h>

// R15: single dispatch (prepass dropped -- R14 showed prep ~5us serial buys
// only ~2us of attn). Theory: R11/R14 are drain/imbalance-bound (Occ 29.7% vs
// 50% cap, aggregate issue ~13%), and staging VALU amortization must come from
// MORE Q-ROWS PER STAGED TILE, not from a prepass.
// Changes vs verified R11 (sync skeleton, swizzles, arithmetic IDENTICAL):
// - 512-thread blocks (8 waves), QT=128: each staged K/V tile feeds 128 q-rows.
//   Staging role-split: waves 0-3 stage V, waves 4-7 stage K -> per-thread
//   staging work halves (same images, same total bytes).
// - grid 512 = 64 ranks x 8 q-slots; pairing perm8={0,1,2,3,7,6,5,4} so under
//   round-robin slot->CU assignment each CU gets complementary strata
//   (nt sums ~ n_k + n_{9-k} = const) -- fixes the 40/32 CU imbalance.
// - LDS 48 KB (KsB 16 + VtB 16 + PsB[8] 16) -> 2 blocks x 8 waves = 16
//   waves/CU (same cap as R11, better retention through the drain).
// Output bit-identical to R11 (verified 38.2us): same staged tile images,
// same Q fragment, same MFMA order, same mask/defer-max/epilogue.

#define NB    64
#define LQ    1024
#define LK    1024
#define DH    64
#define KVT   64
#define QT    128
#define NITEMS (NB * (LQ / QT))      // 512
#define NEGF  1.0e30f
#define SC2   0.18033688011112042f   // 0.125 * log2(e)
#define THR   8.0f                   // defer-max threshold (log2 units)

typedef __attribute__((ext_vector_type(8))) short    bf8;
typedef __attribute__((ext_vector_type(8))) ushort   u16x8;
typedef __attribute__((ext_vector_type(4))) ushort   u16x4;
typedef __attribute__((ext_vector_type(4))) float    f4;

__device__ __forceinline__ ushort2 cvt2(float a, float b) {   // v_cvt_pk_bf16_f32
    float2 f; f.x = a; f.y = b;
    __hip_bfloat162 h = __float22bfloat162_rn(f);
    union { __hip_bfloat162 h2; ushort2 u2; } u;
    u.h2 = h;
    return u.u2;
}
__device__ __forceinline__ int swz16(int row, int colbyte) {  // K, P tiles
    return row * 128 + ((((colbyte >> 4) ^ (row & 7)) << 4) | (colbyte & 15));
}
__device__ __forceinline__ int swz8(int row, int colbyte) {   // V^T tile
    return row * 128 + ((((colbyte >> 3) ^ (row & 15)) << 3) | (colbyte & 7));
}

__global__ __launch_bounds__(512, 4)
void attn_v15(const float* __restrict__ Q, const float* __restrict__ K,
              const float* __restrict__ V, const int* __restrict__ VL,
              float* __restrict__ O) {
    __shared__ ushort KsB[2][KVT * DH];   // swz16 [key][d]      16 KB
    __shared__ ushort VtB[2][DH * KVT];   // swz8  [d][key]      16 KB
    __shared__ ushort PsB[8][16 * KVT];   // swz16 [q][key]/wave 16 KB => 49152

    const int tid = threadIdx.x;
    const int wid = tid >> 6, l = tid & 63, g = l >> 4, a = l & 15;

    // ---- in-kernel stratified-LPT schedule (R11 verbatim; table on PsB) ----
    ushort* sb = &PsB[0][0];              // 64 entries; dead before 1st P write
    if (tid < NB) {
        const int ntb = (VL[tid] + KVT - 1) >> 6;
        int r = 0;
        for (int j = 0; j < NB; ++j) {
            const int ntj = (VL[j] + KVT - 1) >> 6;
            r += (int)((ntj > ntb) | ((ntj == ntb) & (j < tid)));
        }
        sb[r] = (ushort)tid;              // rank -> batch (desc nt, tie asc)
    }
    __syncthreads();
    const int xcd   = blockIdx.x & 7;     // HW: block i -> XCD i%8
    const int slot  = blockIdx.x >> 3;    // 0..63 within XCD
    const int qtile = slot & 7;           // 8 q-slots of 128 rows
    const int st    = slot >> 3;          // stratum 0..7
    // pairing perm: strata (s, s+4) -> (k, 7-k) so round-robin CU pairs sum
    // ~const (n_k + n_{9-k}); perm8 = {0,1,2,3,7,6,5,4}
    const int rank  = xcd + ((st < 4) ? st : (11 - st)) * 8;
    const int b     = sb[rank];
    const int qbase = qtile * QT;
    const int valid = VL[b];              // 1..1024
    const int nt = (valid + KVT - 1) >> 6;

    // Q fragment (B-operand), pre-scaled by SC2: col=a (q-row), k=32kblk+8g+i
    const float* Qr = Q + ((size_t)b * LQ + qbase + wid * 16 + a) * DH;
    bf8 qa[2];
    #pragma unroll
    for (int kblk = 0; kblk < 2; ++kblk) {
        f4 x = *(const f4*)(Qr + kblk * 32 + g * 8);
        f4 y = *(const f4*)(Qr + kblk * 32 + g * 8 + 4);
        ushort2 c0 = cvt2(x[0] * SC2, x[1] * SC2), c1 = cvt2(x[2] * SC2, x[3] * SC2);
        ushort2 c2 = cvt2(y[0] * SC2, y[1] * SC2), c3 = cvt2(y[2] * SC2, y[3] * SC2);
        qa[kblk][0] = (short)c0.x; qa[kblk][1] = (short)c0.y;
        qa[kblk][2] = (short)c1.x; qa[kblk][3] = (short)c1.y;
        qa[kblk][4] = (short)c2.x; qa[kblk][5] = (short)c2.y;
        qa[kblk][6] = (short)c3.x; qa[kblk][7] = (short)c3.y;
    }
    const bf8 ones = {0x3F80, 0x3F80, 0x3F80, 0x3F80,
                      0x3F80, 0x3F80, 0x3F80, 0x3F80};   // bf16 1.0 x8

    // staging roles: waves 0-3 stage V (R11's V part), waves 4-7 stage K
    // (R11's K part). Same tile images, half the per-thread work.
    const int  rtid  = tid & 255;
    const bool vrole = (wid < 4);
    const int srow = rtid >> 3, sslot = rtid & 7;   // K rows srow, srow+32
    const int vkp  = rtid >> 4, vj = rtid & 15;     // V keys 4vkp.., f4-col vj
    const f4* Kb4 = (const f4*)(K + (size_t)b * LK * DH);
    const f4* Vb4 = (const f4*)(V + (size_t)b * LK * DH);

    f4 r0, r1, r2, r3;
    auto load_kv = [&](int k0) {
        if (vrole) {
            r0 = Vb4[(k0 + 4 * vkp + 0) * 16 + vj];
            r1 = Vb4[(k0 + 4 * vkp + 1) * 16 + vj];
            r2 = Vb4[(k0 + 4 * vkp + 2) * 16 + vj];
            r3 = Vb4[(k0 + 4 * vkp + 3) * 16 + vj];
        } else {
            r0 = Kb4[(k0 + srow) * 16 + sslot * 2];
            r1 = Kb4[(k0 + srow) * 16 + sslot * 2 + 1];
            r2 = Kb4[(k0 + srow + 32) * 16 + sslot * 2];
            r3 = Kb4[(k0 + srow + 32) * 16 + sslot * 2 + 1];
        }
    };
    auto store_kv = [&](int bs) {
        if (vrole) {
            char* vd = (char*)&VtB[bs][0];
            #pragma unroll
            for (int c = 0; c < 4; ++c) {      // transpose: d = 4*vj+c
                ushort2 a01 = cvt2(r0[c], r1[c]), a23 = cvt2(r2[c], r3[c]);
                u16x4 p = {a01.x, a01.y, a23.x, a23.y};
                *(u16x4*)(vd + swz8(4 * vj + c, vkp * 8)) = p;
            }
        } else {
            char* kd = (char*)&KsB[bs][0];
            {
                ushort2 c0 = cvt2(r0[0], r0[1]), c1 = cvt2(r0[2], r0[3]);
                ushort2 c2 = cvt2(r1[0], r1[1]), c3 = cvt2(r1[2], r1[3]);
                u16x8 w = {c0.x, c0.y, c1.x, c1.y, c2.x, c2.y, c3.x, c3.y};
                *(u16x8*)(kd + swz16(srow, sslot * 16)) = w;
            }
            {
                ushort2 c0 = cvt2(r2[0], r2[1]), c1 = cvt2(r2[2], r2[3]);
                ushort2 c2 = cvt2(r3[0], r3[1]), c3 = cvt2(r3[2], r3[3]);
                u16x8 w = {c0.x, c0.y, c1.x, c1.y, c2.x, c2.y, c3.x, c3.y};
                *(u16x8*)(kd + swz16(srow + 32, sslot * 16)) = w;
            }
        }
    };

    f4 oacc[4];
    #pragma unroll
    for (int n = 0; n < 4; ++n) oacc[n] = f4{0.f, 0.f, 0.f, 0.f};
    f4 lacc = f4{0.f, 0.f, 0.f, 0.f};   // l per q-row 4g+r (epilogue layout)
    float m_run = -NEGF;                // per-lane: q-row = a

    load_kv(0);
    store_kv(0);
    for (int t = 0; t < nt; ++t) {
        const int bs = t & 1;
        __syncthreads();                         // buf[bs] ready block-wide
        if (t + 1 < nt) load_kv((t + 1) * KVT);  // issue early...
        __builtin_amdgcn_sched_barrier(0);       // ...keep it early

        // ---- S^T = K Q^T (pre-scaled): lane(g,a) -> S[q=a][key=16n+4g+r] ----
        const char* kd = (const char*)&KsB[bs][0];
        f4 sacc[4];
        #pragma unroll
        for (int n = 0; n < 4; ++n) sacc[n] = f4{0.f, 0.f, 0.f, 0.f};
        __builtin_amdgcn_s_setprio(1);
        #pragma unroll
        for (int n = 0; n < 4; ++n)
            #pragma unroll
            for (int kblk = 0; kblk < 2; ++kblk) {
                bf8 kb = *(const bf8*)(kd + swz16(n * 16 + a, kblk * 64 + g * 16));
                sacc[n] = __builtin_amdgcn_mfma_f32_16x16x32_bf16(
                    kb, qa[kblk], sacc[n], 0, 0, 0);   // A=K, B=Q
            }
        __builtin_amdgcn_s_setprio(0);

        float s[4][4];
        const int kmax = valid - t * KVT;
        #pragma unroll
        for (int n = 0; n < 4; ++n)
            #pragma unroll
            for (int r = 0; r < 4; ++r) s[n][r] = sacc[n][r];
        if (kmax < KVT) {
            #pragma unroll
            for (int n = 0; n < 4; ++n)
                #pragma unroll
                for (int r = 0; r < 4; ++r)
                    if (16 * n + 4 * g + r >= kmax) s[n][r] = -NEGF;
        }

        // ---- softmax max: in-lane over 16 keys + 2 shfl over g ----
        float tm = s[0][0];
        #pragma unroll
        for (int n = 0; n < 4; ++n)
            #pragma unroll
            for (int r = 0; r < 4; ++r) tm = fmaxf(tm, s[n][r]);
        tm = fmaxf(tm, __shfl_xor(tm, 16));
        tm = fmaxf(tm, __shfl_xor(tm, 32));

        float rs_ = 1.0f;                     // T13 defer-max
        const bool skip = __all(tm <= m_run + THR);
        if (!skip) {
            const float mnew = fmaxf(m_run, tm);
            rs_ = __builtin_exp2f(m_run - mnew);   // tile0: exp2(-inf)=0
            m_run = mnew;
        }

        float p[4][4];
        #pragma unroll
        for (int n = 0; n < 4; ++n)
            #pragma unroll
            for (int r = 0; r < 4; ++r)
                p[n][r] = __builtin_exp2f(s[n][r] - m_run);   // masked -> 0

        if (!skip) {   // rescale O,l rows (q=4g+r)
            float rr[4];
            #pragma unroll
            for (int r = 0; r < 4; ++r) rr[r] = __shfl(rs_, 4 * g + r);
            #pragma unroll
            for (int n = 0; n < 4; ++n)
                #pragma unroll
                for (int r = 0; r < 4; ++r) oacc[n][r] *= rr[r];
            #pragma unroll
            for (int r = 0; r < 4; ++r) lacc[r] *= rr[r];
        }

        // P -> per-wave LDS: b64 chunks, keys 16n+4g..+3 contiguous
        char* pbase = (char*)&PsB[wid][0];
        #pragma unroll
        for (int n = 0; n < 4; ++n) {
            ushort2 a01 = cvt2(p[n][0], p[n][1]), a23 = cvt2(p[n][2], p[n][3]);
            u16x4 w4 = {a01.x, a01.y, a23.x, a23.y};
            *(u16x4*)(pbase + swz16(a, 32 * n + 8 * g)) = w4;
        }

        // ---- O += P V ; l += P * ones ----
        const char* vd = (const char*)&VtB[bs][0];
        __builtin_amdgcn_s_setprio(1);
        #pragma unroll
        for (int kblk = 0; kblk < 2; ++kblk) {
            bf8 pa = *(const bf8*)(pbase + swz16(a, kblk * 64 + g * 16));
            const int cb = kblk * 64 + g * 16;
            #pragma unroll
            for (int n = 0; n < 4; ++n) {
                u16x4 lo = *(const u16x4*)(vd + swz8(n * 16 + a, cb));
                u16x4 hi = *(const u16x4*)(vd + swz8(n * 16 + a, cb + 8));
                bf8 vb_ = {(short)lo[0], (short)lo[1], (short)lo[2], (short)lo[3],
                           (short)hi[0], (short)hi[1], (short)hi[2], (short)hi[3]};
                oacc[n] = __builtin_amdgcn_mfma_f32_16x16x32_bf16(
                    pa, vb_, oacc[n], 0, 0, 0);
            }
            lacc = __builtin_amdgcn_mfma_f32_16x16x32_bf16(pa, ones, lacc, 0, 0, 0);
        }
        __builtin_amdgcn_s_setprio(0);

        if (t + 1 < nt) store_kv(bs ^ 1);   // post-compute, pre-next-barrier
    }

    // ---- epilogue: O[q=4g+r][d=16n+a] / l (lacc already row-layout) ----
    float iv[4];
    #pragma unroll
    for (int r = 0; r < 4; ++r) iv[r] = 1.0f / lacc[r];
    float* Ob = O + ((size_t)b * LQ + qbase + wid * 16) * DH;
    #pragma unroll
    for (int n = 0; n < 4; ++n)
        #pragma unroll
        for (int r = 0; r < 4; ++r)
            Ob[(size_t)(4 * g + r) * DH + 16 * n + a] = oacc[n][r] * iv[r];
}

extern "C" void kernel_launch(void* const* d_in, const int* in_sizes, int n_in,
                              void* d_out, int out_size, void* d_ws, size_t ws_size,
                              hipStream_t stream) {
    const float* Q  = (const float*)d_in[0];
    const float* K  = (const float*)d_in[1];
    const float* V  = (const float*)d_in[2];
    const int*   VL = (const int*)d_in[3];
    float* O = (float*)d_out;

    attn_v15<<<NITEMS, 512, 0, stream>>>(Q, K, V, VL, O);
}

// Round 5
// 33.590 us; speedup vs baseline: 1.2410x; 1.0568x over previous
//
#include <hip/hip_runtime.h>
#include <hip/hip_bf16.h>

// R16 = R15 + in-register P (P-LDS round-trip eliminated via K-row permutation).
// Insight: QK^T C-layout gives lane (g,a) keys {16n+4g+r}; PV A-operand needs
// keys {32kblk+8g+i}. Mismatch was bridged through PsB (4 ds_write_b64 +
// 2 ds_read_b128 + lgkm per wave-tile). Instead, stage the K tile with rows
// physically permuted: phys(k) = 32*(k>>5) + 16*((k>>2)&1) + 4*((k>>3)&3)
// + (k&3)  (swap key bits 3..4 with bit 2). Then the UNCHANGED QK read
// (phys rows n*16+a) yields lane (g,a) holding exactly keys
// 32*(n>>1) + 4*(n&1) + 8g + r  == the PV A-fragment key set. P assembles
// in registers from the same 8 cvt_pk -- zero LDS, zero lane exchange.
// Changes vs R15 (verified 35.5us): (1) store_kv K-part writes at phys(srow);
// (2) mask key formula 32*(n>>1)+4*(n&1)+8g+r; (3) P-write block deleted,
// pa built in-register; (4) PsB removed -> LDS 32896 (sched table gets its
// own 128B array); QK/PV MFMA order and all roundings identical -> output
// bit-identical to R15/R11.

#define NB    64
#define LQ    1024
#define LK    1024
#define DH    64
#define KVT   64
#define QT    128
#define NITEMS (NB * (LQ / QT))      // 512
#define NEGF  1.0e30f
#define SC2   0.18033688011112042f   // 0.125 * log2(e)
#define THR   8.0f                   // defer-max threshold (log2 units)

typedef __attribute__((ext_vector_type(8))) short    bf8;
typedef __attribute__((ext_vector_type(8))) ushort   u16x8;
typedef __attribute__((ext_vector_type(4))) ushort   u16x4;
typedef __attribute__((ext_vector_type(4))) float    f4;

__device__ __forceinline__ ushort2 cvt2(float a, float b) {   // v_cvt_pk_bf16_f32
    float2 f; f.x = a; f.y = b;
    __hip_bfloat162 h = __float22bfloat162_rn(f);
    union { __hip_bfloat162 h2; ushort2 u2; } u;
    u.h2 = h;
    return u.u2;
}
__device__ __forceinline__ int swz16(int row, int colbyte) {  // K tile
    return row * 128 + ((((colbyte >> 4) ^ (row & 7)) << 4) | (colbyte & 15));
}
__device__ __forceinline__ int swz8(int row, int colbyte) {   // V^T tile
    return row * 128 + ((((colbyte >> 3) ^ (row & 15)) << 3) | (colbyte & 7));
}

__global__ __launch_bounds__(512, 4)
void attn_v16(const float* __restrict__ Q, const float* __restrict__ K,
              const float* __restrict__ V, const int* __restrict__ VL,
              float* __restrict__ O) {
    __shared__ ushort KsB[2][KVT * DH];   // swz16 [phys key][d] 16 KB
    __shared__ ushort VtB[2][DH * KVT];   // swz8  [d][key]      16 KB
    __shared__ ushort sched[NB];          // rank -> batch        128 B => 32896

    const int tid = threadIdx.x;
    const int wid = tid >> 6, l = tid & 63, g = l >> 4, a = l & 15;

    // ---- in-kernel stratified-LPT schedule ----
    if (tid < NB) {
        const int ntb = (VL[tid] + KVT - 1) >> 6;
        int r = 0;
        for (int j = 0; j < NB; ++j) {
            const int ntj = (VL[j] + KVT - 1) >> 6;
            r += (int)((ntj > ntb) | ((ntj == ntb) & (j < tid)));
        }
        sched[r] = (ushort)tid;           // rank -> batch (desc nt, tie asc)
    }
    __syncthreads();
    const int xcd   = blockIdx.x & 7;     // HW: block i -> XCD i%8
    const int slot  = blockIdx.x >> 3;    // 0..63 within XCD
    const int qtile = slot & 7;           // 8 q-slots of 128 rows
    const int st    = slot >> 3;          // stratum 0..7
    // pairing perm8={0,1,2,3,7,6,5,4}: CU gets complementary strata
    const int rank  = xcd + ((st < 4) ? st : (11 - st)) * 8;
    const int b     = sched[rank];
    const int qbase = qtile * QT;
    const int valid = VL[b];              // 1..1024
    const int nt = (valid + KVT - 1) >> 6;

    // Q fragment (B-operand), pre-scaled by SC2: col=a (q-row), k=32kblk+8g+i
    const float* Qr = Q + ((size_t)b * LQ + qbase + wid * 16 + a) * DH;
    bf8 qa[2];
    #pragma unroll
    for (int kblk = 0; kblk < 2; ++kblk) {
        f4 x = *(const f4*)(Qr + kblk * 32 + g * 8);
        f4 y = *(const f4*)(Qr + kblk * 32 + g * 8 + 4);
        ushort2 c0 = cvt2(x[0] * SC2, x[1] * SC2), c1 = cvt2(x[2] * SC2, x[3] * SC2);
        ushort2 c2 = cvt2(y[0] * SC2, y[1] * SC2), c3 = cvt2(y[2] * SC2, y[3] * SC2);
        qa[kblk][0] = (short)c0.x; qa[kblk][1] = (short)c0.y;
        qa[kblk][2] = (short)c1.x; qa[kblk][3] = (short)c1.y;
        qa[kblk][4] = (short)c2.x; qa[kblk][5] = (short)c2.y;
        qa[kblk][6] = (short)c3.x; qa[kblk][7] = (short)c3.y;
    }
    const bf8 ones = {0x3F80, 0x3F80, 0x3F80, 0x3F80,
                      0x3F80, 0x3F80, 0x3F80, 0x3F80};   // bf16 1.0 x8

    // staging roles: waves 0-3 stage V, waves 4-7 stage K (R15 split)
    const int  rtid  = tid & 255;
    const bool vrole = (wid < 4);
    const int srow = rtid >> 3, sslot = rtid & 7;   // K rows srow, srow+32
    const int vkp  = rtid >> 4, vj = rtid & 15;     // V keys 4vkp.., f4-col vj
    // physical LDS row for K key srow (<32): swap bits 3..4 with bit 2;
    // phys(srow+32) = phys(srow)+32.
    const int prow = (srow & 3) | ((srow & 24) >> 1) | ((srow & 4) << 2);
    const f4* Kb4 = (const f4*)(K + (size_t)b * LK * DH);
    const f4* Vb4 = (const f4*)(V + (size_t)b * LK * DH);

    f4 r0, r1, r2, r3;
    auto load_kv = [&](int k0) {
        if (vrole) {
            r0 = Vb4[(k0 + 4 * vkp + 0) * 16 + vj];
            r1 = Vb4[(k0 + 4 * vkp + 1) * 16 + vj];
            r2 = Vb4[(k0 + 4 * vkp + 2) * 16 + vj];
            r3 = Vb4[(k0 + 4 * vkp + 3) * 16 + vj];
        } else {
            r0 = Kb4[(k0 + srow) * 16 + sslot * 2];
            r1 = Kb4[(k0 + srow) * 16 + sslot * 2 + 1];
            r2 = Kb4[(k0 + srow + 32) * 16 + sslot * 2];
            r3 = Kb4[(k0 + srow + 32) * 16 + sslot * 2 + 1];
        }
    };
    auto store_kv = [&](int bs) {
        if (vrole) {
            char* vd = (char*)&VtB[bs][0];
            #pragma unroll
            for (int c = 0; c < 4; ++c) {      // transpose: d = 4*vj+c
                ushort2 a01 = cvt2(r0[c], r1[c]), a23 = cvt2(r2[c], r3[c]);
                u16x4 p = {a01.x, a01.y, a23.x, a23.y};
                *(u16x4*)(vd + swz8(4 * vj + c, vkp * 8)) = p;
            }
        } else {
            char* kd = (char*)&KsB[bs][0];
            {
                ushort2 c0 = cvt2(r0[0], r0[1]), c1 = cvt2(r0[2], r0[3]);
                ushort2 c2 = cvt2(r1[0], r1[1]), c3 = cvt2(r1[2], r1[3]);
                u16x8 w = {c0.x, c0.y, c1.x, c1.y, c2.x, c2.y, c3.x, c3.y};
                *(u16x8*)(kd + swz16(prow, sslot * 16)) = w;
            }
            {
                ushort2 c0 = cvt2(r2[0], r2[1]), c1 = cvt2(r2[2], r2[3]);
                ushort2 c2 = cvt2(r3[0], r3[1]), c3 = cvt2(r3[2], r3[3]);
                u16x8 w = {c0.x, c0.y, c1.x, c1.y, c2.x, c2.y, c3.x, c3.y};
                *(u16x8*)(kd + swz16(prow + 32, sslot * 16)) = w;
            }
        }
    };

    f4 oacc[4];
    #pragma unroll
    for (int n = 0; n < 4; ++n) oacc[n] = f4{0.f, 0.f, 0.f, 0.f};
    f4 lacc = f4{0.f, 0.f, 0.f, 0.f};   // l per q-row 4g+r (epilogue layout)
    float m_run = -NEGF;                // per-lane: q-row = a

    load_kv(0);
    store_kv(0);
    for (int t = 0; t < nt; ++t) {
        const int bs = t & 1;
        __syncthreads();                         // buf[bs] ready block-wide
        if (t + 1 < nt) load_kv((t + 1) * KVT);  // issue early...
        __builtin_amdgcn_sched_barrier(0);       // ...keep it early

        // ---- S^T = K Q^T: phys rows n*16+a => lane (g,a) holds
        //      S[q=a][key = 32*(n>>1) + 4*(n&1) + 8g + r] ----
        const char* kd = (const char*)&KsB[bs][0];
        f4 sacc[4];
        #pragma unroll
        for (int n = 0; n < 4; ++n) sacc[n] = f4{0.f, 0.f, 0.f, 0.f};
        __builtin_amdgcn_s_setprio(1);
        #pragma unroll
        for (int n = 0; n < 4; ++n)
            #pragma unroll
            for (int kblk = 0; kblk < 2; ++kblk) {
                bf8 kb = *(const bf8*)(kd + swz16(n * 16 + a, kblk * 64 + g * 16));
                sacc[n] = __builtin_amdgcn_mfma_f32_16x16x32_bf16(
                    kb, qa[kblk], sacc[n], 0, 0, 0);   // A=K, B=Q
            }
        __builtin_amdgcn_s_setprio(0);

        float s[4][4];
        const int kmax = valid - t * KVT;
        #pragma unroll
        for (int n = 0; n < 4; ++n)
            #pragma unroll
            for (int r = 0; r < 4; ++r) s[n][r] = sacc[n][r];
        if (kmax < KVT) {
            #pragma unroll
            for (int n = 0; n < 4; ++n)
                #pragma unroll
                for (int r = 0; r < 4; ++r)
                    if (32 * (n >> 1) + 4 * (n & 1) + 8 * g + r >= kmax)
                        s[n][r] = -NEGF;
        }

        // ---- softmax max: in-lane over 16 keys + 2 shfl over g ----
        float tm = s[0][0];
        #pragma unroll
        for (int n = 0; n < 4; ++n)
            #pragma unroll
            for (int r = 0; r < 4; ++r) tm = fmaxf(tm, s[n][r]);
        tm = fmaxf(tm, __shfl_xor(tm, 16));
        tm = fmaxf(tm, __shfl_xor(tm, 32));

        float rs_ = 1.0f;                     // T13 defer-max
        const bool skip = __all(tm <= m_run + THR);
        if (!skip) {
            const float mnew = fmaxf(m_run, tm);
            rs_ = __builtin_exp2f(m_run - mnew);   // tile0: exp2(-inf)=0
            m_run = mnew;
        }

        float p[4][4];
        #pragma unroll
        for (int n = 0; n < 4; ++n)
            #pragma unroll
            for (int r = 0; r < 4; ++r)
                p[n][r] = __builtin_exp2f(s[n][r] - m_run);   // masked -> 0

        if (!skip) {   // rescale O,l rows (q=4g+r)
            float rr[4];
            #pragma unroll
            for (int r = 0; r < 4; ++r) rr[r] = __shfl(rs_, 4 * g + r);
            #pragma unroll
            for (int n = 0; n < 4; ++n)
                #pragma unroll
                for (int r = 0; r < 4; ++r) oacc[n][r] *= rr[r];
            #pragma unroll
            for (int r = 0; r < 4; ++r) lacc[r] *= rr[r];
        }

        // ---- O += P V ; l += P * ones  (P assembled IN REGISTERS) ----
        // pa[kblk] = A[row=a][k = 32kblk + 8g + i]: i=0..3 from p[2kblk][r],
        // i=4..7 from p[2kblk+1][r] -- exactly this lane's S keys.
        const char* vd = (const char*)&VtB[bs][0];
        __builtin_amdgcn_s_setprio(1);
        #pragma unroll
        for (int kblk = 0; kblk < 2; ++kblk) {
            ushort2 w0 = cvt2(p[2 * kblk][0], p[2 * kblk][1]);
            ushort2 w1 = cvt2(p[2 * kblk][2], p[2 * kblk][3]);
            ushort2 w2 = cvt2(p[2 * kblk + 1][0], p[2 * kblk + 1][1]);
            ushort2 w3 = cvt2(p[2 * kblk + 1][2], p[2 * kblk + 1][3]);
            bf8 pa = {(short)w0.x, (short)w0.y, (short)w1.x, (short)w1.y,
                      (short)w2.x, (short)w2.y, (short)w3.x, (short)w3.y};
            const int cb = kblk * 64 + g * 16;
            #pragma unroll
            for (int n = 0; n < 4; ++n) {
                u16x4 lo = *(const u16x4*)(vd + swz8(n * 16 + a, cb));
                u16x4 hi = *(const u16x4*)(vd + swz8(n * 16 + a, cb + 8));
                bf8 vb_ = {(short)lo[0], (short)lo[1], (short)lo[2], (short)lo[3],
                           (short)hi[0], (short)hi[1], (short)hi[2], (short)hi[3]};
                oacc[n] = __builtin_amdgcn_mfma_f32_16x16x32_bf16(
                    pa, vb_, oacc[n], 0, 0, 0);
            }
            lacc = __builtin_amdgcn_mfma_f32_16x16x32_bf16(pa, ones, lacc, 0, 0, 0);
        }
        __builtin_amdgcn_s_setprio(0);

        if (t + 1 < nt) store_kv(bs ^ 1);   // post-compute, pre-next-barrier
    }

    // ---- epilogue: O[q=4g+r][d=16n+a] / l (lacc already row-layout) ----
    float iv[4];
    #pragma unroll
    for (int r = 0; r < 4; ++r) iv[r] = 1.0f / lacc[r];
    float* Ob = O + ((size_t)b * LQ + qbase + wid * 16) * DH;
    #pragma unroll
    for (int n = 0; n < 4; ++n)
        #pragma unroll
        for (int r = 0; r < 4; ++r)
            Ob[(size_t)(4 * g + r) * DH + 16 * n + a] = oacc[n][r] * iv[r];
}

extern "C" void kernel_launch(void* const* d_in, const int* in_sizes, int n_in,
                              void* d_out, int out_size, void* d_ws, size_t ws_size,
                              hipStream_t stream) {
    const float* Q  = (const float*)d_in[0];
    const float* K  = (const float*)d_in[1];
    const float* V  = (const float*)d_in[2];
    const int*   VL = (const int*)d_in[3];
    float* O = (float*)d_out;

    attn_v16<<<NITEMS, 512, 0, stream>>>(Q, K, V, VL, O);
}